// Round 5
// baseline (260.624 us; speedup 1.0000x reference)
//
#include <hip/hip_runtime.h>

typedef float v2f __attribute__((ext_vector_type(2)));

#define NEG_INF (-__builtin_huge_valf())
#define NEG_INF_BITS 0xFF800000

// Neighbor fetch via DPP within each 16-lane row (wg axis).
// bound_ctrl=false -> row-boundary lanes take `old` = -inf, which IS the
// W padding at wg==0 (row_shr:1) / wg==15 (row_shl:1). Validated exact r1-r4.
template <int CTRL>
__device__ __forceinline__ float dpp_neighbor(float v) {
    return __int_as_float(__builtin_amdgcn_update_dpp(
        (int)NEG_INF_BITS, __float_as_int(v), CTRL, 0xF, 0xF, false));
}

// elementwise max on packed pair; fmax(fmax) chains still fuse to v_max3/half
__device__ __forceinline__ v2f vmax2(v2f a, v2f b) {
    v2f r; r.x = fmaxf(a.x, b.x); r.y = fmaxf(a.y, b.y); return r;
}

// load 2 channels x 3 rows (6 x float4) for channel group starting at CC+CL0
#define LOADH(DST, CC, CL0)                                                   \
    do {                                                                      \
        _Pragma("unroll") for (int q = 0; q < 2; ++q)                         \
            _Pragma("unroll") for (int r = 0; r < 3; ++r)                     \
                DST[q][r] = *(const float4*)(xb + (((CC) + (CL0) + q) * 4096  \
                                                   + off[r]));                \
    } while (0)

// compute 2 channels from DST against packed taps; acc2 packed over o-pair
#define COMP(SRC, CC, CL0)                                                    \
    do {                                                                      \
        _Pragma("unroll") for (int q = 0; q < 2; ++q) {                       \
            const v2f* kq = &kls[((CC) + (CL0) + q) * 9];                     \
            v2f kk[9];                                                        \
            _Pragma("unroll") for (int t = 0; t < 9; ++t) kk[t] = kq[t];      \
            float xv[3][6];                                                   \
            _Pragma("unroll") for (int r = 0; r < 3; ++r) {                   \
                float4 m = SRC[q][r];                                         \
                if (r != 1 && !rv[r])                                         \
                    m = make_float4(NEG_INF, NEG_INF, NEG_INF, NEG_INF);      \
                xv[r][0] = dpp_neighbor<0x111>(m.w);                          \
                xv[r][1] = m.x; xv[r][2] = m.y;                               \
                xv[r][3] = m.z; xv[r][4] = m.w;                               \
                xv[r][5] = dpp_neighbor<0x101>(m.x);                          \
            }                                                                 \
            _Pragma("unroll") for (int wi = 0; wi < 4; ++wi) {                \
                v2f m = acc2[wi];                                             \
                v2f t0, t1;                                                   \
                t0 = (v2f){xv[0][wi + 0], xv[0][wi + 0]} + kk[0];             \
                t1 = (v2f){xv[0][wi + 1], xv[0][wi + 1]} + kk[1];             \
                m = vmax2(m, vmax2(t0, t1));                                  \
                t0 = (v2f){xv[0][wi + 2], xv[0][wi + 2]} + kk[2];             \
                t1 = (v2f){xv[1][wi + 0], xv[1][wi + 0]} + kk[3];             \
                m = vmax2(m, vmax2(t0, t1));                                  \
                t0 = (v2f){xv[1][wi + 1], xv[1][wi + 1]} + kk[4];             \
                t1 = (v2f){xv[1][wi + 2], xv[1][wi + 2]} + kk[5];             \
                m = vmax2(m, vmax2(t0, t1));                                  \
                t0 = (v2f){xv[2][wi + 0], xv[2][wi + 0]} + kk[6];             \
                t1 = (v2f){xv[2][wi + 1], xv[2][wi + 1]} + kk[7];             \
                m = vmax2(m, vmax2(t0, t1));                                  \
                t0 = (v2f){xv[2][wi + 2], xv[2][wi + 2]} + kk[8];             \
                m = vmax2(m, t0);                                             \
                acc2[wi] = m;                                                 \
            }                                                                 \
        }                                                                     \
    } while (0)

// No LDS for x, no barriers in the main loop. x rows loaded direct from
// global (coalesced 1KB/instr, L1/L2-resident — FETCH proved ideal in r4),
// software-pipelined at half-group granularity via ping-pong reg buffers.
// Kernel taps repacked ONCE per block into LDS as (k[o0],k[o1]) float2
// pairs -> per-chunk tap reads are broadcast ds_read_b64 feeding packed
// v_pk_add_f32 (o-pair packed in float2 lanes), cutting 72 scalar adds/cl
// to 36 pk_adds. Grid (16,8,32) = 4096 single-wave blocks.
__global__ __launch_bounds__(64, 4)
void maxplus_conv2d_kernel(const float* __restrict__ x,
                           const float* __restrict__ kern,
                           float* __restrict__ out) {
    __shared__ v2f kls[64 * 9];   // (c,t) -> (k[o0][c][t], k[o1][c][t]); 4608 B

    const int tid = threadIdx.x;        // 0..63
    const int wg  = tid & 15;
    const int hr  = tid >> 4;           // 0..3
    const int w0  = wg << 2;

    const int h_base = blockIdx.x * 4;
    const int b      = blockIdx.y;
    const int o_base = blockIdx.z << 1; // o pair

    // ---- one-time tap repack (coalesced; single wave -> lgkm dep only) ----
    {
        const float* k0p = kern + (size_t)(o_base + 0) * 576;
        const float* k1p = kern + (size_t)(o_base + 1) * 576;
#pragma unroll
        for (int i = 0; i < 9; ++i) {   // 9*64 = 576 (c,t) pairs
            int idx = i * 64 + tid;
            kls[idx] = (v2f){k0p[idx], k1p[idx]};
        }
    }
    __syncthreads();   // single-wave: compiles to a cheap waitcnt+barrier

    const float* xb = x + (size_t)b * (64 * 64 * 64);

    // Per-lane float offsets; r=1 always valid, r=0/2 may fall outside ->
    // clamped address, value replaced by hoisted-mask cndmask (r4-validated).
    int  off[3];
    bool rv[3];
#pragma unroll
    for (int r = 0; r < 3; ++r) {
        int gh = h_base + hr - 1 + r;
        rv[r]  = (unsigned)gh < 64u;
        off[r] = (rv[r] ? gh : 0) * 64 + w0;
    }

    v2f acc2[4];
#pragma unroll
    for (int wi = 0; wi < 4; ++wi) acc2[wi] = (v2f){NEG_INF, NEG_INF};

    // ping-pong reg buffers: 2 channels x 3 rows each (24 VGPR apiece)
    float4 A[2][3], B2[2][3];
    LOADH(A, 0, 0);                      // prologue: chunk 0, cl {0,1}

#pragma unroll 1
    for (int cc = 0; cc < 64; cc += 4) {
        LOADH(B2, cc, 2);                // cl {2,3} in flight under COMP(A)
        COMP(A, cc, 0);
        if (cc + 4 < 64)
            LOADH(A, cc + 4, 0);         // next chunk's cl {0,1} under COMP(B2)
        COMP(B2, cc, 2);
    }

    const int h = h_base + hr;
    float4 v0 = make_float4(acc2[0].x, acc2[1].x, acc2[2].x, acc2[3].x);
    float4 v1 = make_float4(acc2[0].y, acc2[1].y, acc2[2].y, acc2[3].y);
    *(float4*)(out + ((((size_t)b * 64 + (o_base + 0)) * 64 + h) * 64 + w0)) = v0;
    *(float4*)(out + ((((size_t)b * 64 + (o_base + 1)) * 64 + h) * 64 + w0)) = v1;
}

extern "C" void kernel_launch(void* const* d_in, const int* in_sizes, int n_in,
                              void* d_out, int out_size, void* d_ws, size_t ws_size,
                              hipStream_t stream) {
    const float* x    = (const float*)d_in[0];   // [8,64,64,64]
    const float* kern = (const float*)d_in[1];   // [64,64,3,3]
    float* out = (float*)d_out;                  // [8,64,64,64]

    dim3 grid(16, 8, 32);   // h-tiles, b, o-pairs
    dim3 block(64);
    maxplus_conv2d_kernel<<<grid, block, 0, stream>>>(x, kern, out);
}

// Round 6
// 121.200 us; speedup vs baseline: 2.1504x; 2.1504x over previous
//
#include <hip/hip_runtime.h>

#define NEG_INF (-__builtin_huge_valf())
#define NEG_INF_BITS 0xFF800000

#define CCH   4                 // c's per LDS chunk
#define HB    4                 // output h rows per wave tile
#define ROWS  (HB + 2)          // 6 (h halo)
#define XSTR  64                // xs row stride (floats): pure data, b128-balanced
#define SLOTS 6                 // CCH*ROWS*16 float4 / 64 threads

// Neighbor fetch via DPP within each 16-lane row (wg axis).
// bound_ctrl=false -> row-boundary lanes take `old` = -inf, which IS the
// W padding at wg==0 (row_shr:1) / wg==15 (row_shl:1). Validated exact r1-r4.
template <int CTRL>
__device__ __forceinline__ float dpp_neighbor(float v) {
    return __int_as_float(__builtin_amdgcn_update_dpp(
        (int)NEG_INF_BITS, __float_as_int(v), CTRL, 0xF, 0xF, false));
}

// Round-0 winning skeleton (62.3 us), single delta: the es edge array is
// deleted; the two edge taps per row come from DPP lane neighbors instead.
// Removes per chunk: 12 ds_read2_b32 (+lgkm waits), 12 edge ds_write_b32,
// edge addressing VALU, and ALL 4.76M LDS bank-conflict cycles.
// LDS 10240 -> 6144 B. Everything else byte-identical to round 0.
__global__ __launch_bounds__(64, 4)
void maxplus_conv2d_kernel(const float* __restrict__ x,
                           const float* __restrict__ kern,
                           float* __restrict__ out) {
    __shared__ float xs[CCH * ROWS * XSTR];   // 6144 B

    const int tid = threadIdx.x;        // 0..63
    const int wg  = tid & 15;
    const int hr  = tid >> 4;           // 0..3
    const int w0  = wg << 2;

    const int h_base = blockIdx.x * HB;
    const int b      = blockIdx.y;
    const int o_base = blockIdx.z << 1; // o pair

    // ---- staging slots (chunk-invariant; computed once) ----
    const float* xb = x + (size_t)b * 64 * 64 * 64;
    const float* gsrc[SLOTS];
    float*       xdst[SLOTS];
    bool         vmask[SLOTS];
#pragma unroll
    for (int k = 0; k < SLOTS; ++k) {
        int rowid = k * 4 + hr;           // 0..23, each exactly once per wave
        int cl    = rowid / ROWS;
        int r     = rowid - cl * ROWS;
        int gh    = h_base + r - 1;       // -1..64
        bool valid = (unsigned)gh < 64u;
        int  ghc   = valid ? gh : 0;      // clamped (no OOB); value replaced by -inf
        gsrc[k]  = xb + ((size_t)cl * 64 + ghc) * 64 + wg * 4;
        xdst[k]  = &xs[rowid * XSTR + wg * 4];   // aligned ds_write_b128
        vmask[k] = valid;
    }

    float acc[2][4];
#pragma unroll
    for (int oo = 0; oo < 2; ++oo)
#pragma unroll
        for (int wi = 0; wi < 4; ++wi)
            acc[oo][wi] = NEG_INF;

    // prefetch chunk 0
    float4 R[SLOTS];
#pragma unroll
    for (int k = 0; k < SLOTS; ++k) R[k] = *(const float4*)gsrc[k];

#pragma unroll 1
    for (int cc = 0; cc < 64; cc += CCH) {
        __syncthreads();   // WAR fence: prev chunk's reads before these writes

#pragma unroll
        for (int k = 0; k < SLOTS; ++k) {
            float4 v = R[k];
            if (!vmask[k]) v = make_float4(NEG_INF, NEG_INF, NEG_INF, NEG_INF);
            *(float4*)xdst[k] = v;        // cols w0..w0+3
        }

        __syncthreads();   // RAW fence: writes visible before cross-lane reads

        if (cc + CCH < 64) {   // prefetch next chunk; vmcnt rides under compute
#pragma unroll
            for (int k = 0; k < SLOTS; ++k) {
                gsrc[k] += CCH * 64 * 64;
                R[k] = *(const float4*)gsrc[k];
            }
        }

        // batch tap loads for the whole chunk (wave-uniform -> grouped s_loads)
        float kv[CCH][2][9];
#pragma unroll
        for (int cl = 0; cl < CCH; ++cl)
#pragma unroll
            for (int oo = 0; oo < 2; ++oo) {
                const float* kp = kern + ((size_t)(o_base + oo) * 64 + (cc + cl)) * 9;
#pragma unroll
                for (int t = 0; t < 9; ++t) kv[cl][oo][t] = kp[t];
            }

#pragma unroll
        for (int cl = 0; cl < CCH; ++cl) {
            // x window: 3 rows x [DPP edge | w0..w0+3 b128 | DPP edge]
            float xv[3][6];
#pragma unroll
            for (int r = 0; r < 3; ++r) {
                const int rowid = cl * ROWS + hr + r;
                float4 m = *(const float4*)(&xs[rowid * XSTR + w0]);
                xv[r][0] = dpp_neighbor<0x111>(m.w);  // row_shr:1 -> left edge
                xv[r][1] = m.x; xv[r][2] = m.y; xv[r][3] = m.z; xv[r][4] = m.w;
                xv[r][5] = dpp_neighbor<0x101>(m.x);  // row_shl:1 -> right edge
            }

#pragma unroll
            for (int oo = 0; oo < 2; ++oo) {
                const float* k9 = kv[cl][oo];
#pragma unroll
                for (int wi = 0; wi < 4; ++wi) {
                    float m = acc[oo][wi];
                    // paired -> v_max3_f32: 9 add + 4 max3 + 1 max per out per c
                    float t0 = xv[0][wi + 0] + k9[0];
                    float t1 = xv[0][wi + 1] + k9[1];
                    m = fmaxf(m, fmaxf(t0, t1));
                    t0 = xv[0][wi + 2] + k9[2];
                    t1 = xv[1][wi + 0] + k9[3];
                    m = fmaxf(m, fmaxf(t0, t1));
                    t0 = xv[1][wi + 1] + k9[4];
                    t1 = xv[1][wi + 2] + k9[5];
                    m = fmaxf(m, fmaxf(t0, t1));
                    t0 = xv[2][wi + 0] + k9[6];
                    t1 = xv[2][wi + 1] + k9[7];
                    m = fmaxf(m, fmaxf(t0, t1));
                    m = fmaxf(m, xv[2][wi + 2] + k9[8]);
                    acc[oo][wi] = m;
                }
            }
        }
    }

    const int h = h_base + hr;
#pragma unroll
    for (int oo = 0; oo < 2; ++oo) {
        float4 v = make_float4(acc[oo][0], acc[oo][1], acc[oo][2], acc[oo][3]);
        *(float4*)(out + ((((size_t)b * 64 + (o_base + oo)) * 64 + h) * 64 + w0)) = v;
    }
}

extern "C" void kernel_launch(void* const* d_in, const int* in_sizes, int n_in,
                              void* d_out, int out_size, void* d_ws, size_t ws_size,
                              hipStream_t stream) {
    const float* x    = (const float*)d_in[0];   // [8,64,64,64]
    const float* kern = (const float*)d_in[1];   // [64,64,3,3]
    float* out = (float*)d_out;                  // [8,64,64,64]

    dim3 grid(16, 8, 32);   // h-tiles, b, o-pairs
    dim3 block(64);
    maxplus_conv2d_kernel<<<grid, block, 0, stream>>>(x, kern, out);
}